// Round 1
// baseline (339.654 us; speedup 1.0000x reference)
//
#include <hip/hip_runtime.h>
#include <math.h>

// Problem geometry (fixed by the reference):
//   x: [N=512, 3, 3, NUM=128, FRAME=100] f32
//   y: [N, 3, 3, NUM/2=64, FRAME] f32
//   y[n,i,j,g,f] = x[n,i,j,2g+I,f] where I = argmax over pair {2g,2g+1} of
//   rotation-angle r_a(trace), first-max-wins (so I=1 only on strict >).

namespace {

constexpr int N_     = 512;
constexpr int NUM_   = 128;
constexpr int FRAME_ = 100;
constexpr int G_     = NUM_ / 2;   // 64
constexpr int F4_    = FRAME_ / 4; // 25 float4 groups per frame row
constexpr int TOTAL_ = N_ * G_ * F4_;  // 819200 threads

constexpr int       X_IJ = NUM_ * FRAME_;        // 12800
constexpr int       X_M  = FRAME_;               // 100
constexpr long long X_N  = 9LL * X_IJ;           // 115200
constexpr int       Y_IJ = G_ * FRAME_;          // 6400
constexpr long long Y_N  = 9LL * Y_IJ;           // 57600

__device__ __forceinline__ float rot_angle(float tr) {
    // Faithful replication of cal_roc_angel_batch's masking:
    //   maskpi   = (|tr+1| > eps) & (|tr-3| <= eps)  -> tr*pi
    //   maskacos = (|tr+1| <= eps)                   -> acos(tr)
    const float eps = 1e-12f;
    float r = 0.0f;
    bool maskpi = (fabsf(tr + 1.0f) > eps) && (fabsf(tr - 3.0f) <= eps);
    bool maskacos = fabsf(tr + 1.0f) <= eps;
    if (maskpi)   r += tr * 3.14159265358979323846f;
    if (maskacos) r += acosf(tr);
    return r;
}

__global__ __launch_bounds__(256) void pool_space_kernel(
        const float* __restrict__ x, float* __restrict__ y) {
    int idx = blockIdx.x * blockDim.x + threadIdx.x;
    if (idx >= TOTAL_) return;

    int f4 = idx % F4_;
    int t  = idx / F4_;
    int g  = t % G_;
    int n  = t / G_;
    int f  = f4 * 4;

    const float* xb = x + (long long)n * X_N + (2 * g) * X_M + f;

    // Diagonal elements of both candidate matrices (4 frames each).
    float4 a00 = *(const float4*)(xb + 0 * X_IJ);
    float4 a11 = *(const float4*)(xb + 4 * X_IJ);
    float4 a22 = *(const float4*)(xb + 8 * X_IJ);
    float4 b00 = *(const float4*)(xb + 0 * X_IJ + X_M);
    float4 b11 = *(const float4*)(xb + 4 * X_IJ + X_M);
    float4 b22 = *(const float4*)(xb + 8 * X_IJ + X_M);

    float ra0 = rot_angle(a00.x + a11.x + a22.x);
    float ra1 = rot_angle(a00.y + a11.y + a22.y);
    float ra2 = rot_angle(a00.z + a11.z + a22.z);
    float ra3 = rot_angle(a00.w + a11.w + a22.w);
    float rb0 = rot_angle(b00.x + b11.x + b22.x);
    float rb1 = rot_angle(b00.y + b11.y + b22.y);
    float rb2 = rot_angle(b00.z + b11.z + b22.z);
    float rb3 = rot_angle(b00.w + b11.w + b22.w);

    // argmax over {a,b} with first-max-wins: pick b only on strict >.
    bool s0 = rb0 > ra0;
    bool s1 = rb1 > ra1;
    bool s2 = rb2 > ra2;
    bool s3 = rb3 > ra3;

    float* yb = y + (long long)n * Y_N + g * FRAME_ + f;

    if (s0 == s1 && s1 == s2 && s2 == s3) {
        // Uniform selection across the 4 frames: copy only the winner.
        const float* xs = xb + (s0 ? X_M : 0);
#pragma unroll
        for (int k = 0; k < 9; ++k) {
            float4 v = *(const float4*)(xs + k * X_IJ);
            *(float4*)(yb + k * Y_IJ) = v;
        }
    } else {
        // Mixed selection: component-wise select (still bit-exact copies).
#pragma unroll
        for (int k = 0; k < 9; ++k) {
            float4 va = *(const float4*)(xb + k * X_IJ);
            float4 vb = *(const float4*)(xb + k * X_IJ + X_M);
            float4 v;
            v.x = s0 ? vb.x : va.x;
            v.y = s1 ? vb.y : va.y;
            v.z = s2 ? vb.z : va.z;
            v.w = s3 ? vb.w : va.w;
            *(float4*)(yb + k * Y_IJ) = v;
        }
    }
}

} // namespace

extern "C" void kernel_launch(void* const* d_in, const int* in_sizes, int n_in,
                              void* d_out, int out_size, void* d_ws, size_t ws_size,
                              hipStream_t stream) {
    const float* x = (const float*)d_in[0];
    float* y = (float*)d_out;
    dim3 block(256);
    dim3 grid((TOTAL_ + 255) / 256);
    hipLaunchKernelGGL(pool_space_kernel, grid, block, 0, stream, x, y);
}

// Round 2
// 324.989 us; speedup vs baseline: 1.0451x; 1.0451x over previous
//
#include <hip/hip_runtime.h>
#include <math.h>

// Problem geometry (fixed by the reference):
//   x: [N=512, 3, 3, NUM=128, FRAME=100] f32
//   y: [N, 3, 3, NUM/2=64, FRAME] f32
//   y[n,i,j,g,f] = x[n,i,j,2g+I,f] where I = argmax over pair {2g,2g+1} of
//   rotation-angle r_a(trace), first-max-wins (I=1 only on strict >).
//
// Traffic floor: diag of both candidates (157 MB incl. winner overlap) +
// winner non-diag (78.6 MB) reads + 118 MB writes ≈ 275 MB ≈ 44 us @ 6.3 TB/s.

namespace {

constexpr int N_     = 512;
constexpr int NUM_   = 128;
constexpr int FRAME_ = 100;
constexpr int G_     = NUM_ / 2;   // 64
constexpr int F4_    = FRAME_ / 4; // 25 float4 groups per frame row
constexpr int TOTAL_ = N_ * G_ * F4_;  // 819200 threads

constexpr int       X_IJ = NUM_ * FRAME_;        // 12800
constexpr int       X_M  = FRAME_;               // 100
constexpr long long X_N  = 9LL * X_IJ;           // 115200
constexpr int       Y_IJ = G_ * FRAME_;          // 6400
constexpr long long Y_N  = 9LL * Y_IJ;           // 57600

typedef float v4f __attribute__((ext_vector_type(4)));

__device__ __forceinline__ v4f ntload4(const float* p) {
    return __builtin_nontemporal_load((const v4f*)p);
}
__device__ __forceinline__ void ntstore4(float* p, v4f v) {
    __builtin_nontemporal_store(v, (v4f*)p);
}

__device__ __forceinline__ float rot_angle(float tr) {
    // Faithful replication of cal_roc_angel_batch's masking:
    //   maskpi   = (|tr+1| > eps) & (|tr-3| <= eps)  -> tr*pi
    //   maskacos = (|tr+1| <= eps)                   -> acos(tr)
    const float eps = 1e-12f;
    float r = 0.0f;
    bool maskpi = (fabsf(tr + 1.0f) > eps) && (fabsf(tr - 3.0f) <= eps);
    bool maskacos = fabsf(tr + 1.0f) <= eps;
    if (maskpi)   r += tr * 3.14159265358979323846f;
    if (maskacos) r += acosf(tr);
    return r;
}

__global__ __launch_bounds__(256) void pool_space_kernel(
        const float* __restrict__ x, float* __restrict__ y) {
    int idx = blockIdx.x * blockDim.x + threadIdx.x;
    if (idx >= TOTAL_) return;

    int f4 = idx % F4_;
    int t  = idx / F4_;
    int g  = t % G_;
    int n  = t / G_;
    int f  = f4 * 4;

    const float* xb = x + (long long)n * X_N + (2 * g) * X_M + f;

    // Diagonal elements of both candidates (4 frames each) — kept in regs,
    // reused as the copy source for rows k=0,4,8 (no reload).
    v4f a00 = ntload4(xb + 0 * X_IJ);
    v4f a11 = ntload4(xb + 4 * X_IJ);
    v4f a22 = ntload4(xb + 8 * X_IJ);
    v4f b00 = ntload4(xb + 0 * X_IJ + X_M);
    v4f b11 = ntload4(xb + 4 * X_IJ + X_M);
    v4f b22 = ntload4(xb + 8 * X_IJ + X_M);

    v4f trA = a00 + a11 + a22;
    v4f trB = b00 + b11 + b22;

    // argmax over {a,b} with first-max-wins: pick b only on strict >.
    bool s0 = rot_angle(trB.x) > rot_angle(trA.x);
    bool s1 = rot_angle(trB.y) > rot_angle(trA.y);
    bool s2 = rot_angle(trB.z) > rot_angle(trA.z);
    bool s3 = rot_angle(trB.w) > rot_angle(trA.w);

    float* yb = y + (long long)n * Y_N + g * FRAME_ + f;

    if (s0 == s1 && s1 == s2 && s2 == s3) {
        // Uniform selection across the 4 frames: touch only the winner.
        const float* xs = xb + (s0 ? X_M : 0);
        // Diagonal rows straight from registers.
        ntstore4(yb + 0 * Y_IJ, s0 ? b00 : a00);
        ntstore4(yb + 4 * Y_IJ, s0 ? b11 : a11);
        ntstore4(yb + 8 * Y_IJ, s0 ? b22 : a22);
        // Off-diagonal rows: 6 streaming load+store, loads issued first (ILP).
        v4f v1 = ntload4(xs + 1 * X_IJ);
        v4f v2 = ntload4(xs + 2 * X_IJ);
        v4f v3 = ntload4(xs + 3 * X_IJ);
        v4f v5 = ntload4(xs + 5 * X_IJ);
        v4f v6 = ntload4(xs + 6 * X_IJ);
        v4f v7 = ntload4(xs + 7 * X_IJ);
        ntstore4(yb + 1 * Y_IJ, v1);
        ntstore4(yb + 2 * Y_IJ, v2);
        ntstore4(yb + 3 * Y_IJ, v3);
        ntstore4(yb + 5 * Y_IJ, v5);
        ntstore4(yb + 6 * Y_IJ, v6);
        ntstore4(yb + 7 * Y_IJ, v7);
    } else {
        // Mixed selection: component-wise select (still bit-exact copies).
        v4f d0, d1, d2;
        d0.x = s0 ? b00.x : a00.x; d0.y = s1 ? b00.y : a00.y;
        d0.z = s2 ? b00.z : a00.z; d0.w = s3 ? b00.w : a00.w;
        d1.x = s0 ? b11.x : a11.x; d1.y = s1 ? b11.y : a11.y;
        d1.z = s2 ? b11.z : a11.z; d1.w = s3 ? b11.w : a11.w;
        d2.x = s0 ? b22.x : a22.x; d2.y = s1 ? b22.y : a22.y;
        d2.z = s2 ? b22.z : a22.z; d2.w = s3 ? b22.w : a22.w;
        ntstore4(yb + 0 * Y_IJ, d0);
        ntstore4(yb + 4 * Y_IJ, d1);
        ntstore4(yb + 8 * Y_IJ, d2);
        const int ks[6] = {1, 2, 3, 5, 6, 7};
#pragma unroll
        for (int q = 0; q < 6; ++q) {
            int k = ks[q];
            v4f va = ntload4(xb + k * X_IJ);
            v4f vb = ntload4(xb + k * X_IJ + X_M);
            v4f v;
            v.x = s0 ? vb.x : va.x;
            v.y = s1 ? vb.y : va.y;
            v.z = s2 ? vb.z : va.z;
            v.w = s3 ? vb.w : va.w;
            ntstore4(yb + k * Y_IJ, v);
        }
    }
}

} // namespace

extern "C" void kernel_launch(void* const* d_in, const int* in_sizes, int n_in,
                              void* d_out, int out_size, void* d_ws, size_t ws_size,
                              hipStream_t stream) {
    const float* x = (const float*)d_in[0];
    float* y = (float*)d_out;
    dim3 block(256);
    dim3 grid((TOTAL_ + 255) / 256);
    hipLaunchKernelGGL(pool_space_kernel, grid, block, 0, stream, x, y);
}